// Round 14
// baseline (1129.729 us; speedup 1.0000x reference)
//
#include <hip/hip_runtime.h>
#include <stdint.h>

#define T_SEQ 256
#define NB    8
#define EMB   512
#define HID   1024
#define NOUT  32000
#define RING  16
#define SEN   0x40004000u
#define NSTRIP 250

typedef float    f32x4  __attribute__((ext_vector_type(4)));
typedef unsigned int u32x4 __attribute__((ext_vector_type(4)));
typedef __bf16   bf16x8 __attribute__((ext_vector_type(8)));

#define AS1 __attribute__((address_space(1)))
#define AS3 __attribute__((address_space(3)))

__device__ __forceinline__ uint32_t f2bf(float f) {
    uint32_t u = __builtin_bit_cast(uint32_t, f);
    u += 0x7FFFu + ((u >> 16) & 1u);   // RNE
    return (u >> 16);
}

__device__ __forceinline__ bf16x8 mk_hi(u32x4 a, u32x4 b) {
    u32x4 r;
    r.x = __builtin_amdgcn_perm(a.y, a.x, 0x07060302u);
    r.y = __builtin_amdgcn_perm(a.w, a.z, 0x07060302u);
    r.z = __builtin_amdgcn_perm(b.y, b.x, 0x07060302u);
    r.w = __builtin_amdgcn_perm(b.w, b.z, 0x07060302u);
    return __builtin_bit_cast(bf16x8, r);
}
__device__ __forceinline__ bf16x8 mk_lo(u32x4 a, u32x4 b) {
    u32x4 r;
    r.x = __builtin_amdgcn_perm(a.y, a.x, 0x05040100u);
    r.y = __builtin_amdgcn_perm(a.w, a.z, 0x05040100u);
    r.z = __builtin_amdgcn_perm(b.y, b.x, 0x05040100u);
    r.w = __builtin_amdgcn_perm(b.w, b.z, 0x05040100u);
    return __builtin_bit_cast(bf16x8, r);
}

// ---------------- sentinel fill of the packed-h rings (R6/R11-proven) ----------------
__global__ void k_fill(unsigned int* __restrict__ p) {   // 8*RING*1024 u32 = 512 KB
    int i = blockIdx.x * blockDim.x + threadIdx.x;       // 128 x 256 x 4
    unsigned int* a = p + (size_t)i * 4;
#pragma unroll
    for (int j = 0; j < 4; ++j)
        (void)__hip_atomic_exchange(a + j, SEN, __ATOMIC_RELAXED, __HIP_MEMORY_SCOPE_AGENT);
}

// ---------------- W_fc fp32 -> bf16 (R11-proven; near-free at full machine) ----------------
__global__ void k_convert_wfc(const float* __restrict__ src, unsigned short* __restrict__ dst) {
    int i = blockIdx.x * blockDim.x + threadIdx.x;
    const f32x4* s4 = (const f32x4*)src;
    int n4 = NOUT * HID / 4;
    int stride = gridDim.x * blockDim.x;
    for (int idx = i; idx < n4; idx += stride) {
        f32x4 v = s4[idx];
        uint2 o;
        o.x = f2bf(v.x) | (f2bf(v.y) << 16);
        o.y = f2bf(v.z) | (f2bf(v.w) << 16);
        ((uint2*)dst)[idx] = o;
    }
}

// ---------------- embed gather + xproj = emb @ W_ih^T + b_ih (fp32) ----------------
__global__ __launch_bounds__(256) void k_xproj(
        const int* __restrict__ inputs, const float* __restrict__ embed,
        const float* __restrict__ W_ih, const float* __restrict__ b_ih,
        float* __restrict__ xproj) {
    __shared__ float As[64][33];
    __shared__ float Bs[64][33];
    __shared__ int   idx_s[64];
    const int tid = threadIdx.x;
    const int bm = blockIdx.y, bn = blockIdx.x;
    if (tid < 64) {
        int m = bm * 64 + tid;
        idx_s[tid] = inputs[(m & 7) * T_SEQ + (m >> 3)];
    }
    __syncthreads();
    const int ty = tid >> 4, tx = tid & 15;
    const int lr = tid >> 2, lc = (tid & 3) * 8;
    float acc[4][4] = {};
    for (int kk = 0; kk < EMB; kk += 32) {
        __syncthreads();
        const float* arow = embed + (size_t)idx_s[lr] * EMB + kk + lc;
        f32x4 a0 = *(const f32x4*)arow;
        f32x4 a1 = *(const f32x4*)(arow + 4);
        const float* brow = W_ih + (size_t)(bn * 64 + lr) * EMB + kk + lc;
        f32x4 b0 = *(const f32x4*)brow;
        f32x4 b1 = *(const f32x4*)(brow + 4);
#pragma unroll
        for (int u = 0; u < 4; ++u) {
            As[lr][lc + u] = a0[u]; As[lr][lc + 4 + u] = a1[u];
            Bs[lr][lc + u] = b0[u]; Bs[lr][lc + 4 + u] = b1[u];
        }
        __syncthreads();
#pragma unroll
        for (int k = 0; k < 32; ++k) {
            float av[4], bv[4];
#pragma unroll
            for (int i = 0; i < 4; ++i) av[i] = As[ty * 4 + i][k];
#pragma unroll
            for (int j = 0; j < 4; ++j) bv[j] = Bs[tx * 4 + j][k];
#pragma unroll
            for (int i = 0; i < 4; ++i)
#pragma unroll
                for (int j = 0; j < 4; ++j) acc[i][j] += av[i] * bv[j];
        }
    }
#pragma unroll
    for (int i = 0; i < 4; ++i) {
        int m = bm * 64 + ty * 4 + i;
#pragma unroll
        for (int j = 0; j < 4; ++j) {
            int n = bn * 64 + tx * 4 + j;
            xproj[(size_t)m * HID + n] = acc[i][j] + b_ih[n];
        }
    }
}

// ============ mega: blocks 0-255 = R11 rnn; blocks 256-511 = fc workers ============
// rnn role: R11-verbatim sentinel-ring recurrence; hs stores write-through; each
// member's wave0 bumps chaincnt[chain] after barrier-1 (the step-t poll's vmcnt(0)
// already drained step t-1's hs stores -> free release ordering).
// fc role: bn-major strips via ticket; per-bm gate on chaincnt >= 512*(bm+1);
// tile body = R11 k_fc verbatim. Deadlock-impossible: counters are monotone and
// advanced unconditionally by rnn; rnn never waits on fc.
#define DO_CHUNK(qa, qb, WH, WL, ACC) do {                                      \
    bf16x8 ah = mk_hi(qa, qb);                                                  \
    bf16x8 al = mk_lo(qa, qb);                                                  \
    ACC = __builtin_amdgcn_mfma_f32_16x16x32_bf16(ah, WH, ACC, 0, 0, 0);        \
    ACC = __builtin_amdgcn_mfma_f32_16x16x32_bf16(al, WH, ACC, 0, 0, 0);        \
    ACC = __builtin_amdgcn_mfma_f32_16x16x32_bf16(ah, WL, ACC, 0, 0, 0);        \
} while (0)

__global__ __launch_bounds__(256, 2) void k_mega(
        const float* __restrict__ W_hh, const float* __restrict__ b_hh,
        const float* __restrict__ xproj,
        unsigned int* __restrict__ hpk /* [8][RING][1024] u32 */,
        unsigned short* __restrict__ hs /* [2048][1024] bf16 */,
        const unsigned short* __restrict__ wfcb /* [32000][1024] bf16 */,
        const float* __restrict__ b_fc,
        float* __restrict__ out,
        unsigned int* __restrict__ chaincnt /* [8] on 128B-strided lines */,
        unsigned int* __restrict__ ticket) {
    __shared__ __align__(16) char smem[16896];
    const int tid = threadIdx.x;
    const int w   = tid >> 6;
    const int ln  = tid & 63;
    const int blk = blockIdx.x;

    if (blk < 256) {
        // ================= RNN role (R11 verbatim + progress adds) =================
        unsigned int* hlds = (unsigned int*)smem;                 // 4 KB
        float (*part)[4][16] = (float (*)[4][16])(smem + 4096);   // [2][4][16]
        const int chain  = blk >> 5;
        const int member = blk & 31;
        const int cg = w & 1;
        const int kh = w >> 1;
        const int col0 = member * 32 + cg * 16;
        unsigned int* ring = hpk + (size_t)chain * (RING * 1024);
        unsigned int* cc_p = chaincnt + chain * 32;

        const float* wrow = W_hh + (size_t)(col0 + (ln & 15)) * HID;
        bf16x8 whi[16], wlo[16];
#pragma unroll
        for (int cc = 0; cc < 16; ++cc) {
            int k0 = kh * 512 + cc * 32 + (ln >> 4) * 8;
            f32x4 wa = *(const f32x4*)(wrow + k0);
            f32x4 wb = *(const f32x4*)(wrow + k0 + 4);
            float wv[8] = { wa.x, wa.y, wa.z, wa.w, wb.x, wb.y, wb.z, wb.w };
            uint32_t hu[8], lu[8];
#pragma unroll
            for (int j = 0; j < 8; ++j) {
                hu[j] = f2bf(wv[j]);
                float hif = __builtin_bit_cast(float, hu[j] << 16);
                lu[j] = f2bf(wv[j] - hif);
            }
            u32x4 ph = { hu[0] | (hu[1] << 16), hu[2] | (hu[3] << 16),
                         hu[4] | (hu[5] << 16), hu[6] | (hu[7] << 16) };
            u32x4 pl = { lu[0] | (lu[1] << 16), lu[2] | (lu[3] << 16),
                         lu[4] | (lu[5] << 16), lu[6] | (lu[7] << 16) };
            whi[cc] = __builtin_bit_cast(bf16x8, ph);
            wlo[cc] = __builtin_bit_cast(bf16x8, pl);
        }
        const float bhh = (ln < 16) ? b_hh[col0 + ln] : 0.f;

        for (int t = 0; t < T_SEQ; ++t) {
            float xp = 0.f;
            if (kh == 0 && ln < 16)
                xp = xproj[(size_t)(t * NB + chain) * HID + col0 + ln];

            if (t > 0) {
                const unsigned int* hp = ring + (size_t)((t - 1) & (RING - 1)) * 1024
                                              + w * 256 + ln * 4;
                u32x4 q;
                do {
                    asm volatile("global_load_dwordx4 %0, %1, off sc0 sc1\n\t"
                                 "s_waitcnt vmcnt(0)"
                                 : "=&v"(q) : "v"(hp) : "memory");
                } while (q.x == SEN || q.y == SEN || q.z == SEN || q.w == SEN);
                *(u32x4*)&hlds[w * 256 + ln * 4] = q;
            }
            __syncthreads();   // BARRIER 1: h_{t-1} staged; all waves' vmcnt drained
            // progress: this member's hs stores through t-1 are globally visible
            if (t > 0 && tid == 0)
                (void)__hip_atomic_fetch_add(cc_p, 1u,
                                             __ATOMIC_RELAXED, __HIP_MEMORY_SCOPE_AGENT);

            f32x4 acc0 = {0.f, 0.f, 0.f, 0.f}, acc1 = {0.f, 0.f, 0.f, 0.f};
            if (t > 0) {
                const int lsub = (ln >> 4) * 8;
#pragma unroll
                for (int cc = 0; cc < 16; ++cc) {
                    int ab = kh * 512 + cc * 32 + lsub;
                    u32x4 qa = *(const u32x4*)&hlds[ab];
                    u32x4 qb = *(const u32x4*)&hlds[ab + 4];
                    if (cc & 1) { DO_CHUNK(qa, qb, whi[cc], wlo[cc], acc1); }
                    else        { DO_CHUNK(qa, qb, whi[cc], wlo[cc], acc0); }
                }
            }
            if (ln < 16) part[t & 1][w][ln] = acc0.x + acc1.x;
            __syncthreads();   // BARRIER 2

            if (kh == 0 && ln < 16) {
                float sum = part[t & 1][w][ln] + part[t & 1][w + 2][ln];
                int colp = col0 + ln;
                float x = xp + sum + bhh;
                float h = tanhf(x);
                uint32_t hi = f2bf(h);
                float hif = __builtin_bit_cast(float, hi << 16);
                uint32_t lo = f2bf(h - hif);
                uint32_t pk = (hi << 16) | lo;
                (void)__hip_atomic_exchange(ring + (size_t)(t & (RING - 1)) * 1024 + colp,
                                            pk, __ATOMIC_RELAXED, __HIP_MEMORY_SCOPE_AGENT);
                (void)__hip_atomic_exchange(ring + (size_t)((t + RING - 3) & (RING - 1)) * 1024 + colp,
                                            SEN, __ATOMIC_RELAXED, __HIP_MEMORY_SCOPE_AGENT);
                // hs archive: write-through so co-running fc workers can read it
                unsigned short* aa = hs + (size_t)(t * NB + chain) * HID + colp;
                asm volatile("global_store_short %0, %1, off sc0 sc1"
                             :: "v"(aa), "v"(hi) : "memory");
            }
        }
        // final release: drain last hs stores, then the step-255 completion add
        asm volatile("s_waitcnt vmcnt(0)" ::: "memory");
        __syncthreads();
        if (tid == 0)
            (void)__hip_atomic_fetch_add(cc_p, 1u,
                                         __ATOMIC_RELAXED, __HIP_MEMORY_SCOPE_AGENT);
        return;
    }

    // ================= FC worker role (blocks 256-511) =================
    unsigned short* As = (unsigned short*)smem;            // 8 KB [128][32]
    unsigned short* Bs = (unsigned short*)(smem + 8192);   // 8 KB [128][32]
    int* ticket_s = (int*)(smem + 16384);
    const int wm = (w >> 1) * 64, wn = (w & 1) * 64;
    const int fr = ln & 15;
    const int kq = (ln >> 4) * 8;
    const int srow = tid >> 2;
    const int scol = (tid & 3) * 8;

    for (;;) {
        __syncthreads();
        if (tid == 0) *ticket_s = (int)atomicAdd(ticket, 1u);
        __syncthreads();
        int bn = *ticket_s;
        if (bn >= NSTRIP) break;

        const unsigned short* Bg = wfcb + (size_t)(bn * 128 + srow) * 1024 + scol;

        for (int bm = 0; bm < 16; ++bm) {
            // gate: all 8 chains' counters >= 512*(bm+1)  (hs rows complete)
            if (w == 0) {
                unsigned int thr = 512u * (unsigned int)(bm + 1);
                const unsigned int* cp = chaincnt + (ln & 7) * 32;
                for (;;) {
                    unsigned int v;
                    asm volatile("global_load_dword %0, %1, off sc0 sc1\n\t"
                                 "s_waitcnt vmcnt(0)"
                                 : "=v"(v) : "v"(cp) : "memory");
                    bool ok = (ln < 8) ? (v >= thr) : true;
                    if (__all(ok)) break;
                    __builtin_amdgcn_s_sleep(16);
                }
            }
            __syncthreads();

            const unsigned short* Ag = hs + (size_t)(bm * 128 + srow) * 1024 + scol;
            unsigned short* ldsA0 = As + w * 512;
            unsigned short* ldsA1 = As + 2048 + w * 512;
            unsigned short* ldsB0 = Bs + w * 512;
            unsigned short* ldsB1 = Bs + 2048 + w * 512;

            f32x4 acc[4][4] = {};
            for (int kk = 0; kk < 1024; kk += 32) {
                __syncthreads();
                __builtin_amdgcn_global_load_lds((const AS1 void*)(Ag + kk),             (AS3 void*)ldsA0, 16, 0, 0);
                __builtin_amdgcn_global_load_lds((const AS1 void*)(Ag + 64 * 1024 + kk), (AS3 void*)ldsA1, 16, 0, 0);
                __builtin_amdgcn_global_load_lds((const AS1 void*)(Bg + kk),             (AS3 void*)ldsB0, 16, 0, 0);
                __builtin_amdgcn_global_load_lds((const AS1 void*)(Bg + 64 * 1024 + kk), (AS3 void*)ldsB1, 16, 0, 0);
                __syncthreads();
                bf16x8 af[4], bfj[4];
#pragma unroll
                for (int i = 0; i < 4; ++i)
                    af[i] = *(const bf16x8*)&As[(wm + i * 16 + fr) * 32 + kq];
#pragma unroll
                for (int j = 0; j < 4; ++j)
                    bfj[j] = *(const bf16x8*)&Bs[(wn + j * 16 + fr) * 32 + kq];
#pragma unroll
                for (int i = 0; i < 4; ++i)
#pragma unroll
                    for (int j = 0; j < 4; ++j)
                        acc[i][j] = __builtin_amdgcn_mfma_f32_16x16x32_bf16(af[i], bfj[j], acc[i][j], 0, 0, 0);
            }

            const int fq = ln >> 4;
#pragma unroll
            for (int i = 0; i < 4; ++i) {
#pragma unroll
                for (int j = 0; j < 4; ++j) {
                    int n = bn * 128 + wn + j * 16 + fr;
                    float bv = b_fc[n];
#pragma unroll
                    for (int r = 0; r < 4; ++r) {
                        int m = bm * 128 + wm + i * 16 + fq * 4 + r;
                        int t = m >> 3, b = m & 7;
                        out[(size_t)b * T_SEQ * NOUT + (size_t)t * NOUT + n] = acc[i][j][r] + bv;
                    }
                }
            }
            __syncthreads();   // As/Bs reuse safe for next bm
        }
    }
}

extern "C" void kernel_launch(void* const* d_in, const int* in_sizes, int n_in,
                              void* d_out, int out_size, void* d_ws, size_t ws_size,
                              hipStream_t stream) {
    const int*   inputs = (const int*)d_in[0];
    const float* embed  = (const float*)d_in[1];
    const float* W_ih   = (const float*)d_in[2];
    const float* W_hh   = (const float*)d_in[3];
    const float* b_ih   = (const float*)d_in[4];
    const float* b_hh   = (const float*)d_in[5];
    const float* W_fc   = (const float*)d_in[6];
    const float* b_fc   = (const float*)d_in[7];
    float* out = (float*)d_out;

    char* ws = (char*)d_ws;
    unsigned int*   chaincnt = (unsigned int*)(ws);                  // 8 x 128B lines
    unsigned int*   ticket   = (unsigned int*)(ws + 2048);
    unsigned int*   hpk      = (unsigned int*)(ws + 4096);           // 512 KB
    float*          xproj    = (float*)(ws + 4096 + 524288);         // 8 MB
    unsigned short* hs       = (unsigned short*)(ws + 4096 + 524288 + 8388608);           // 4 MB
    unsigned short* wfcb     = (unsigned short*)(ws + 4096 + 524288 + 8388608 + 4194304); // 64 MB

    hipMemsetAsync(ws, 0, 4096, stream);
    k_fill<<<128, 256, 0, stream>>>(hpk);
    k_convert_wfc<<<2048, 256, 0, stream>>>(W_fc, wfcb);
    k_xproj<<<dim3(16, 32), 256, 0, stream>>>(inputs, embed, W_ih, b_ih, xproj);
    k_mega<<<512, 256, 0, stream>>>(W_hh, b_hh, xproj, hpk, hs,
                                    wfcb, b_fc, out, chaincnt, ticket);
}

// Round 16
// 773.014 us; speedup vs baseline: 1.4615x; 1.4615x over previous
//
#include <hip/hip_runtime.h>
#include <stdint.h>

#define T_SEQ 256
#define NB    8
#define EMB   512
#define HID   1024
#define NOUT  32000
#define RING  16
#define SEN   0x40004000u

typedef float    f32x4  __attribute__((ext_vector_type(4)));
typedef unsigned int u32x4 __attribute__((ext_vector_type(4)));
typedef __bf16   bf16x8 __attribute__((ext_vector_type(8)));

#define AS1 __attribute__((address_space(1)))
#define AS3 __attribute__((address_space(3)))

__device__ __forceinline__ uint32_t f2bf(float f) {
    uint32_t u = __builtin_bit_cast(uint32_t, f);
    u += 0x7FFFu + ((u >> 16) & 1u);   // RNE
    return (u >> 16);
}

__device__ __forceinline__ bf16x8 mk_hi(u32x4 a, u32x4 b) {
    u32x4 r;
    r.x = __builtin_amdgcn_perm(a.y, a.x, 0x07060302u);
    r.y = __builtin_amdgcn_perm(a.w, a.z, 0x07060302u);
    r.z = __builtin_amdgcn_perm(b.y, b.x, 0x07060302u);
    r.w = __builtin_amdgcn_perm(b.w, b.z, 0x07060302u);
    return __builtin_bit_cast(bf16x8, r);
}
__device__ __forceinline__ bf16x8 mk_lo(u32x4 a, u32x4 b) {
    u32x4 r;
    r.x = __builtin_amdgcn_perm(a.y, a.x, 0x05040100u);
    r.y = __builtin_amdgcn_perm(a.w, a.z, 0x05040100u);
    r.z = __builtin_amdgcn_perm(b.y, b.x, 0x05040100u);
    r.w = __builtin_amdgcn_perm(b.w, b.z, 0x05040100u);
    return __builtin_bit_cast(bf16x8, r);
}

// ======== prologue: blocks 0-127 fill ring; 128-639 xproj; 640-2047 convert ========
// Three proven roles concatenated; no inter-role dependencies. Everything k_rnn
// and k_fc need is complete at the kernel boundary.
__global__ __launch_bounds__(256) void k_prologue(
        const int* __restrict__ inputs, const float* __restrict__ embed,
        const float* __restrict__ W_ih, const float* __restrict__ b_ih,
        float* __restrict__ xproj,
        unsigned int* __restrict__ hpk,                 // 8*RING*1024 u32 = 512 KB
        const float* __restrict__ W_fc, unsigned short* __restrict__ wfcb) {
    const int blk = blockIdx.x;
    const int tid = threadIdx.x;

    if (blk < 128) {
        // ---- ring sentinel fill (R6/R11-proven atomic-exchange form) ----
        int i = blk * 256 + tid;
        unsigned int* a = hpk + (size_t)i * 4;
#pragma unroll
        for (int j = 0; j < 4; ++j)
            (void)__hip_atomic_exchange(a + j, SEN, __ATOMIC_RELAXED, __HIP_MEMORY_SCOPE_AGENT);
        return;
    }

    if (blk < 640) {
        // ---- xproj role (R11 k_xproj verbatim; bm/bn from linear index) ----
        __shared__ float As[64][33];
        __shared__ float Bs[64][33];
        __shared__ int   idx_s[64];
        const int idx = blk - 128;
        const int bm = idx >> 4, bn = idx & 15;
        if (tid < 64) {
            int m = bm * 64 + tid;
            idx_s[tid] = inputs[(m & 7) * T_SEQ + (m >> 3)];
        }
        __syncthreads();
        const int ty = tid >> 4, tx = tid & 15;
        const int lr = tid >> 2, lc = (tid & 3) * 8;
        float acc[4][4] = {};
        for (int kk = 0; kk < EMB; kk += 32) {
            __syncthreads();
            const float* arow = embed + (size_t)idx_s[lr] * EMB + kk + lc;
            f32x4 a0 = *(const f32x4*)arow;
            f32x4 a1 = *(const f32x4*)(arow + 4);
            const float* brow = W_ih + (size_t)(bn * 64 + lr) * EMB + kk + lc;
            f32x4 b0 = *(const f32x4*)brow;
            f32x4 b1 = *(const f32x4*)(brow + 4);
#pragma unroll
            for (int u = 0; u < 4; ++u) {
                As[lr][lc + u] = a0[u]; As[lr][lc + 4 + u] = a1[u];
                Bs[lr][lc + u] = b0[u]; Bs[lr][lc + 4 + u] = b1[u];
            }
            __syncthreads();
#pragma unroll
            for (int k = 0; k < 32; ++k) {
                float av[4], bv[4];
#pragma unroll
                for (int i = 0; i < 4; ++i) av[i] = As[ty * 4 + i][k];
#pragma unroll
                for (int j = 0; j < 4; ++j) bv[j] = Bs[tx * 4 + j][k];
#pragma unroll
                for (int i = 0; i < 4; ++i)
#pragma unroll
                    for (int j = 0; j < 4; ++j) acc[i][j] += av[i] * bv[j];
            }
        }
#pragma unroll
        for (int i = 0; i < 4; ++i) {
            int m = bm * 64 + ty * 4 + i;
#pragma unroll
            for (int j = 0; j < 4; ++j) {
                int n = bn * 64 + tx * 4 + j;
                xproj[(size_t)m * HID + n] = acc[i][j] + b_ih[n];
            }
        }
        return;
    }

    // ---- W_fc fp32 -> bf16 convert role (grid-stride over 1408 blocks) ----
    {
        int i = (blk - 640) * 256 + tid;
        const f32x4* s4 = (const f32x4*)W_fc;
        int n4 = NOUT * HID / 4;
        int stride = 1408 * 256;
        for (int idx2 = i; idx2 < n4; idx2 += stride) {
            f32x4 v = s4[idx2];
            uint2 o;
            o.x = f2bf(v.x) | (f2bf(v.y) << 16);
            o.y = f2bf(v.z) | (f2bf(v.w) << 16);
            ((uint2*)wfcb)[idx2] = o;
        }
    }
}

// ========== recurrence: 8 batch-chains x 32 blocks x 32 cols — R11 VERBATIM ==========
// Counted-vmcnt polling is BLACKLISTED (R12, R15 both silently corrupted h).
// Only the single-load + s_waitcnt vmcnt(0) poll has ever passed. Do not change.
#define DO_CHUNK(qa, qb, WH, WL, ACC) do {                                      \
    bf16x8 ah = mk_hi(qa, qb);                                                  \
    bf16x8 al = mk_lo(qa, qb);                                                  \
    ACC = __builtin_amdgcn_mfma_f32_16x16x32_bf16(ah, WH, ACC, 0, 0, 0);        \
    ACC = __builtin_amdgcn_mfma_f32_16x16x32_bf16(al, WH, ACC, 0, 0, 0);        \
    ACC = __builtin_amdgcn_mfma_f32_16x16x32_bf16(ah, WL, ACC, 0, 0, 0);        \
} while (0)

__global__ __launch_bounds__(256, 1) void k_rnn(
        const float* __restrict__ W_hh, const float* __restrict__ b_hh,
        const float* __restrict__ xproj,
        unsigned int* __restrict__ hpk /* [8][RING][1024] u32 */,
        unsigned short* __restrict__ hs /* [2048][1024] bf16 */) {
    __shared__ __align__(16) unsigned int hlds[1024];   // 4 KB: chain's h_{t-1}
    __shared__ float part[2][4][16];                     // partial join
    const int tid = threadIdx.x;
    const int w   = tid >> 6;
    const int ln  = tid & 63;
    const int blk = blockIdx.x;
    const int chain  = blk >> 5;
    const int member = blk & 31;
    const int cg = w & 1;
    const int kh = w >> 1;
    const int col0 = member * 32 + cg * 16;
    unsigned int* ring = hpk + (size_t)chain * (RING * 1024);

    const float* wrow = W_hh + (size_t)(col0 + (ln & 15)) * HID;
    bf16x8 whi[16], wlo[16];
#pragma unroll
    for (int cc = 0; cc < 16; ++cc) {
        int k0 = kh * 512 + cc * 32 + (ln >> 4) * 8;
        f32x4 wa = *(const f32x4*)(wrow + k0);
        f32x4 wb = *(const f32x4*)(wrow + k0 + 4);
        float wv[8] = { wa.x, wa.y, wa.z, wa.w, wb.x, wb.y, wb.z, wb.w };
        uint32_t hu[8], lu[8];
#pragma unroll
        for (int j = 0; j < 8; ++j) {
            hu[j] = f2bf(wv[j]);
            float hif = __builtin_bit_cast(float, hu[j] << 16);
            lu[j] = f2bf(wv[j] - hif);
        }
        u32x4 ph = { hu[0] | (hu[1] << 16), hu[2] | (hu[3] << 16),
                     hu[4] | (hu[5] << 16), hu[6] | (hu[7] << 16) };
        u32x4 pl = { lu[0] | (lu[1] << 16), lu[2] | (lu[3] << 16),
                     lu[4] | (lu[5] << 16), lu[6] | (lu[7] << 16) };
        whi[cc] = __builtin_bit_cast(bf16x8, ph);
        wlo[cc] = __builtin_bit_cast(bf16x8, pl);
    }
    const float bhh = (ln < 16) ? b_hh[col0 + ln] : 0.f;

    for (int t = 0; t < T_SEQ; ++t) {
        float xp = 0.f;
        if (kh == 0 && ln < 16)
            xp = xproj[(size_t)(t * NB + chain) * HID + col0 + ln];

        // poll own 1KB quarter of chain's h_{t-1}: ONE dwordx4 per lane, vmcnt(0)
        if (t > 0) {
            const unsigned int* hp = ring + (size_t)((t - 1) & (RING - 1)) * 1024
                                          + w * 256 + ln * 4;
            u32x4 q;
            do {
                asm volatile("global_load_dwordx4 %0, %1, off sc0 sc1\n\t"
                             "s_waitcnt vmcnt(0)"
                             : "=&v"(q) : "v"(hp) : "memory");
            } while (q.x == SEN || q.y == SEN || q.z == SEN || q.w == SEN);
            *(u32x4*)&hlds[w * 256 + ln * 4] = q;
        }
        __syncthreads();   // BARRIER 1: h_{t-1} staged

        f32x4 acc0 = {0.f, 0.f, 0.f, 0.f}, acc1 = {0.f, 0.f, 0.f, 0.f};
        if (t > 0) {
            const int lsub = (ln >> 4) * 8;
#pragma unroll
            for (int cc = 0; cc < 16; ++cc) {
                int ab = kh * 512 + cc * 32 + lsub;
                u32x4 qa = *(const u32x4*)&hlds[ab];
                u32x4 qb = *(const u32x4*)&hlds[ab + 4];
                if (cc & 1) { DO_CHUNK(qa, qb, whi[cc], wlo[cc], acc1); }
                else        { DO_CHUNK(qa, qb, whi[cc], wlo[cc], acc0); }
            }
        }
        if (ln < 16) part[t & 1][w][ln] = acc0.x + acc1.x;
        __syncthreads();   // BARRIER 2: partials ready; hlds reusable

        if (kh == 0 && ln < 16) {
            float sum = part[t & 1][w][ln] + part[t & 1][w + 2][ln];
            int colp = col0 + ln;
            float x = xp + sum + bhh;
            float h = tanhf(x);
            uint32_t hi = f2bf(h);
            float hif = __builtin_bit_cast(float, hi << 16);
            uint32_t lo = f2bf(h - hif);
            uint32_t pk = (hi << 16) | lo;
            (void)__hip_atomic_exchange(ring + (size_t)(t & (RING - 1)) * 1024 + colp,
                                        pk, __ATOMIC_RELAXED, __HIP_MEMORY_SCOPE_AGENT);
            (void)__hip_atomic_exchange(ring + (size_t)((t + RING - 3) & (RING - 1)) * 1024 + colp,
                                        SEN, __ATOMIC_RELAXED, __HIP_MEMORY_SCOPE_AGENT);
            hs[(size_t)(t * NB + chain) * HID + colp] = (unsigned short)hi;
        }
    }
}

// ---------------- fc: C[m][n] = hs[m][:] . W_fc[n][:] + b_fc[n], bf16 MFMA ----------------
// R11 verbatim. grid dim3(16,250): bm fast -> B-tile consumers dispatch adjacently.
__global__ void k_fc(const unsigned short* __restrict__ A,   // [2048][1024] bf16
                     const unsigned short* __restrict__ Bw,  // [32000][1024] bf16
                     const float* __restrict__ bias,
                     float* __restrict__ out) {              // [8][256][32000] f32
    __shared__ __align__(16) unsigned short As[128 * 32];
    __shared__ __align__(16) unsigned short Bs[128 * 32];
    const int tid = threadIdx.x;
    const int w = tid >> 6, ln = tid & 63;
    const int bm = blockIdx.x, bn = blockIdx.y;
    const int wm = (w >> 1) * 64, wn = (w & 1) * 64;
    const int srow = tid >> 2;
    const int scol = (tid & 3) * 8;
    const unsigned short* Ag = A  + (size_t)(bm * 128 + srow) * 1024 + scol;
    const unsigned short* Bg = Bw + (size_t)(bn * 128 + srow) * 1024 + scol;
    unsigned short* ldsA0 = As + w * 512;
    unsigned short* ldsA1 = As + 2048 + w * 512;
    unsigned short* ldsB0 = Bs + w * 512;
    unsigned short* ldsB1 = Bs + 2048 + w * 512;

    f32x4 acc[4][4] = {};
    const int fr = ln & 15;
    const int kq = (ln >> 4) * 8;

    for (int kk = 0; kk < 1024; kk += 32) {
        __syncthreads();
        __builtin_amdgcn_global_load_lds((const AS1 void*)(Ag + kk),             (AS3 void*)ldsA0, 16, 0, 0);
        __builtin_amdgcn_global_load_lds((const AS1 void*)(Ag + 64 * 1024 + kk), (AS3 void*)ldsA1, 16, 0, 0);
        __builtin_amdgcn_global_load_lds((const AS1 void*)(Bg + kk),             (AS3 void*)ldsB0, 16, 0, 0);
        __builtin_amdgcn_global_load_lds((const AS1 void*)(Bg + 64 * 1024 + kk), (AS3 void*)ldsB1, 16, 0, 0);
        __syncthreads();
        bf16x8 af[4], bf[4];
#pragma unroll
        for (int i = 0; i < 4; ++i)
            af[i] = *(const bf16x8*)&As[(wm + i * 16 + fr) * 32 + kq];
#pragma unroll
        for (int j = 0; j < 4; ++j)
            bf[j] = *(const bf16x8*)&Bs[(wn + j * 16 + fr) * 32 + kq];
#pragma unroll
        for (int i = 0; i < 4; ++i)
#pragma unroll
            for (int j = 0; j < 4; ++j)
                acc[i][j] = __builtin_amdgcn_mfma_f32_16x16x32_bf16(af[i], bf[j], acc[i][j], 0, 0, 0);
    }

    const int fq = ln >> 4;
#pragma unroll
    for (int i = 0; i < 4; ++i) {
#pragma unroll
        for (int j = 0; j < 4; ++j) {
            int n = bn * 128 + wn + j * 16 + fr;
            float bv = bias[n];
#pragma unroll
            for (int r = 0; r < 4; ++r) {
                int m = bm * 128 + wm + i * 16 + fq * 4 + r;
                int t = m >> 3, b = m & 7;
                out[(size_t)b * T_SEQ * NOUT + (size_t)t * NOUT + n] = acc[i][j][r] + bv;
            }
        }
    }
}

extern "C" void kernel_launch(void* const* d_in, const int* in_sizes, int n_in,
                              void* d_out, int out_size, void* d_ws, size_t ws_size,
                              hipStream_t stream) {
    const int*   inputs = (const int*)d_in[0];
    const float* embed  = (const float*)d_in[1];
    const float* W_ih   = (const float*)d_in[2];
    const float* W_hh   = (const float*)d_in[3];
    const float* b_ih   = (const float*)d_in[4];
    const float* b_hh   = (const float*)d_in[5];
    const float* W_fc   = (const float*)d_in[6];
    const float* b_fc   = (const float*)d_in[7];
    float* out = (float*)d_out;

    char* ws = (char*)d_ws;
    unsigned int*   hpk   = (unsigned int*)(ws);                        // 512 KB
    float*          xproj = (float*)(ws + 524288);                      // 8 MB
    unsigned short* hs    = (unsigned short*)(ws + 524288 + 8388608);   // 4 MB
    unsigned short* wfcb  = (unsigned short*)(ws + 524288 + 8388608 + 4194304); // 64 MB

    k_prologue<<<2048, 256, 0, stream>>>(inputs, embed, W_ih, b_ih, xproj,
                                         hpk, W_fc, wfcb);
    k_rnn<<<256, 256, 0, stream>>>(W_hh, b_hh, xproj, hpk, hs);
    k_fc<<<dim3(16, 250), 256, 0, stream>>>(hs, wfcb, b_fc, out);
}

// Round 17
// 674.014 us; speedup vs baseline: 1.6761x; 1.1469x over previous
//
#include <hip/hip_runtime.h>
#include <stdint.h>

#define T_SEQ 256
#define NB    8
#define EMB   512
#define HID   1024
#define NOUT  32000
#define RING  16
#define SEN   0x40004000u

typedef float    f32x4  __attribute__((ext_vector_type(4)));
typedef unsigned int u32x4 __attribute__((ext_vector_type(4)));
typedef __bf16   bf16x8 __attribute__((ext_vector_type(8)));

#define AS1 __attribute__((address_space(1)))
#define AS3 __attribute__((address_space(3)))

__device__ __forceinline__ uint32_t f2bf(float f) {
    uint32_t u = __builtin_bit_cast(uint32_t, f);
    u += 0x7FFFu + ((u >> 16) & 1u);   // RNE
    return (u >> 16);
}

__device__ __forceinline__ bf16x8 mk_hi(u32x4 a, u32x4 b) {
    u32x4 r;
    r.x = __builtin_amdgcn_perm(a.y, a.x, 0x07060302u);
    r.y = __builtin_amdgcn_perm(a.w, a.z, 0x07060302u);
    r.z = __builtin_amdgcn_perm(b.y, b.x, 0x07060302u);
    r.w = __builtin_amdgcn_perm(b.w, b.z, 0x07060302u);
    return __builtin_bit_cast(bf16x8, r);
}
__device__ __forceinline__ bf16x8 mk_lo(u32x4 a, u32x4 b) {
    u32x4 r;
    r.x = __builtin_amdgcn_perm(a.y, a.x, 0x05040100u);
    r.y = __builtin_amdgcn_perm(a.w, a.z, 0x05040100u);
    r.z = __builtin_amdgcn_perm(b.y, b.x, 0x05040100u);
    r.w = __builtin_amdgcn_perm(b.w, b.z, 0x05040100u);
    return __builtin_bit_cast(bf16x8, r);
}

// ======== prologue: blocks 0-127 fill ring; 128-639 xproj; 640-2047 convert ========
// R16 verbatim (proven).
__global__ __launch_bounds__(256) void k_prologue(
        const int* __restrict__ inputs, const float* __restrict__ embed,
        const float* __restrict__ W_ih, const float* __restrict__ b_ih,
        float* __restrict__ xproj,
        unsigned int* __restrict__ hpk,                 // 8*RING*1024 u32 = 512 KB
        const float* __restrict__ W_fc, unsigned short* __restrict__ wfcb) {
    const int blk = blockIdx.x;
    const int tid = threadIdx.x;

    if (blk < 128) {
        int i = blk * 256 + tid;
        unsigned int* a = hpk + (size_t)i * 4;
#pragma unroll
        for (int j = 0; j < 4; ++j)
            (void)__hip_atomic_exchange(a + j, SEN, __ATOMIC_RELAXED, __HIP_MEMORY_SCOPE_AGENT);
        return;
    }

    if (blk < 640) {
        __shared__ float As[64][33];
        __shared__ float Bs[64][33];
        __shared__ int   idx_s[64];
        const int idx = blk - 128;
        const int bm = idx >> 4, bn = idx & 15;
        if (tid < 64) {
            int m = bm * 64 + tid;
            idx_s[tid] = inputs[(m & 7) * T_SEQ + (m >> 3)];
        }
        __syncthreads();
        const int ty = tid >> 4, tx = tid & 15;
        const int lr = tid >> 2, lc = (tid & 3) * 8;
        float acc[4][4] = {};
        for (int kk = 0; kk < EMB; kk += 32) {
            __syncthreads();
            const float* arow = embed + (size_t)idx_s[lr] * EMB + kk + lc;
            f32x4 a0 = *(const f32x4*)arow;
            f32x4 a1 = *(const f32x4*)(arow + 4);
            const float* brow = W_ih + (size_t)(bn * 64 + lr) * EMB + kk + lc;
            f32x4 b0 = *(const f32x4*)brow;
            f32x4 b1 = *(const f32x4*)(brow + 4);
#pragma unroll
            for (int u = 0; u < 4; ++u) {
                As[lr][lc + u] = a0[u]; As[lr][lc + 4 + u] = a1[u];
                Bs[lr][lc + u] = b0[u]; Bs[lr][lc + 4 + u] = b1[u];
            }
            __syncthreads();
#pragma unroll
            for (int k = 0; k < 32; ++k) {
                float av[4], bv[4];
#pragma unroll
                for (int i = 0; i < 4; ++i) av[i] = As[ty * 4 + i][k];
#pragma unroll
                for (int j = 0; j < 4; ++j) bv[j] = Bs[tx * 4 + j][k];
#pragma unroll
                for (int i = 0; i < 4; ++i)
#pragma unroll
                    for (int j = 0; j < 4; ++j) acc[i][j] += av[i] * bv[j];
            }
        }
#pragma unroll
        for (int i = 0; i < 4; ++i) {
            int m = bm * 64 + ty * 4 + i;
#pragma unroll
            for (int j = 0; j < 4; ++j) {
                int n = bn * 64 + tx * 4 + j;
                xproj[(size_t)m * HID + n] = acc[i][j] + b_ih[n];
            }
        }
        return;
    }

    {
        int i = (blk - 640) * 256 + tid;
        const f32x4* s4 = (const f32x4*)W_fc;
        int n4 = NOUT * HID / 4;
        int stride = 1408 * 256;
        for (int idx2 = i; idx2 < n4; idx2 += stride) {
            f32x4 v = s4[idx2];
            uint2 o;
            o.x = f2bf(v.x) | (f2bf(v.y) << 16);
            o.y = f2bf(v.z) | (f2bf(v.w) << 16);
            ((uint2*)wfcb)[idx2] = o;
        }
    }
}

// ========== recurrence: 8 chains x 32 blocks; waves = K-QUARTERS (R17) ==========
// Coherence primitives bit-identical to R11/R16 (single-load vmcnt(0) poll,
// atomic-exchange publish + sentinel refill; counted-vmcnt BLACKLISTED).
// New partition: wave w owns K-quarter [w*256, w*256+256) for ALL 32 block cols.
// Its poll fetches exactly what it MFMAs -> staging is WAVE-PRIVATE LDS
// (no BARRIER 1). In-wave RAW ordered by lgkmcnt(0)+sched_barrier(0) (DS pipe
// is in-order per wave). Single barrier/step = the part join; wave0-only
// epilogue overlaps waves 1-3's next poll.
#define DO_CHUNK(qa, qb, WH, WL, ACC) do {                                      \
    bf16x8 ah = mk_hi(qa, qb);                                                  \
    bf16x8 al = mk_lo(qa, qb);                                                  \
    ACC = __builtin_amdgcn_mfma_f32_16x16x32_bf16(ah, WH, ACC, 0, 0, 0);        \
    ACC = __builtin_amdgcn_mfma_f32_16x16x32_bf16(al, WH, ACC, 0, 0, 0);        \
    ACC = __builtin_amdgcn_mfma_f32_16x16x32_bf16(ah, WL, ACC, 0, 0, 0);        \
} while (0)

__global__ __launch_bounds__(256, 1) void k_rnn(
        const float* __restrict__ W_hh, const float* __restrict__ b_hh,
        const float* __restrict__ xproj,
        unsigned int* __restrict__ hpk /* [8][RING][1024] u32 */,
        unsigned short* __restrict__ hs /* [2048][1024] bf16 */) {
    __shared__ __align__(16) unsigned int hlds[1024];   // 4 KB, wave-private quarters
    __shared__ float part[2][4][32];                     // 1 KB join, dbuf by t&1
    const int tid = threadIdx.x;
    const int w   = tid >> 6;
    const int ln  = tid & 63;
    const int blk = blockIdx.x;
    const int chain  = blk >> 5;
    const int member = blk & 31;
    const int col0 = member * 32;
    unsigned int* ring = hpk + (size_t)chain * (RING * 1024);

    // W fragments: col-group A (col0..+15) and B (col0+16..+31), K-quarter w.
    // 8 chunks x 2 groups x hi/lo = 32 bf16x8 = 128 VGPR.
    const float* wrowA = W_hh + (size_t)(col0 + (ln & 15)) * HID;
    const float* wrowB = W_hh + (size_t)(col0 + 16 + (ln & 15)) * HID;
    bf16x8 whiA[8], wloA[8], whiB[8], wloB[8];
#pragma unroll
    for (int cc = 0; cc < 8; ++cc) {
        int k0 = w * 256 + cc * 32 + (ln >> 4) * 8;
#pragma unroll
        for (int g = 0; g < 2; ++g) {
            const float* wr = g ? wrowB : wrowA;
            f32x4 wa = *(const f32x4*)(wr + k0);
            f32x4 wb = *(const f32x4*)(wr + k0 + 4);
            float wv[8] = { wa.x, wa.y, wa.z, wa.w, wb.x, wb.y, wb.z, wb.w };
            uint32_t hu[8], lu[8];
#pragma unroll
            for (int j = 0; j < 8; ++j) {
                hu[j] = f2bf(wv[j]);
                float hif = __builtin_bit_cast(float, hu[j] << 16);
                lu[j] = f2bf(wv[j] - hif);
            }
            u32x4 ph = { hu[0] | (hu[1] << 16), hu[2] | (hu[3] << 16),
                         hu[4] | (hu[5] << 16), hu[6] | (hu[7] << 16) };
            u32x4 pl = { lu[0] | (lu[1] << 16), lu[2] | (lu[3] << 16),
                         lu[4] | (lu[5] << 16), lu[6] | (lu[7] << 16) };
            if (g) { whiB[cc] = __builtin_bit_cast(bf16x8, ph); wloB[cc] = __builtin_bit_cast(bf16x8, pl); }
            else   { whiA[cc] = __builtin_bit_cast(bf16x8, ph); wloA[cc] = __builtin_bit_cast(bf16x8, pl); }
        }
    }
    const float bhh = (w == 0 && ln < 32) ? b_hh[col0 + ln] : 0.f;

    for (int t = 0; t < T_SEQ; ++t) {
        // xproj prefetch (epilogue wave), hidden under the poll
        float xp = 0.f;
        if (w == 0 && ln < 32)
            xp = xproj[(size_t)(t * NB + chain) * HID + col0 + ln];

        if (t > 0) {
            // poll own K-quarter: ONE dwordx4 per lane, vmcnt(0) (R11-proven form)
            const unsigned int* hp = ring + (size_t)((t - 1) & (RING - 1)) * 1024
                                          + w * 256 + ln * 4;
            u32x4 q;
            do {
                asm volatile("global_load_dwordx4 %0, %1, off sc0 sc1\n\t"
                             "s_waitcnt vmcnt(0)"
                             : "=&v"(q) : "v"(hp) : "memory");
            } while (q.x == SEN || q.y == SEN || q.z == SEN || q.w == SEN);
            // wave-private stage; in-wave RAW fence (rule #18 pattern)
            *(u32x4*)&hlds[w * 256 + ln * 4] = q;
            asm volatile("s_waitcnt lgkmcnt(0)" ::: "memory");
            __builtin_amdgcn_sched_barrier(0);
        }

        f32x4 aA0 = {0.f,0.f,0.f,0.f}, aA1 = {0.f,0.f,0.f,0.f};
        f32x4 aB0 = {0.f,0.f,0.f,0.f}, aB1 = {0.f,0.f,0.f,0.f};
        if (t > 0) {
            const int lsub = (ln >> 4) * 8;
#pragma unroll
            for (int cc = 0; cc < 8; ++cc) {
                int ab = w * 256 + cc * 32 + lsub;
                u32x4 qa = *(const u32x4*)&hlds[ab];
                u32x4 qb = *(const u32x4*)&hlds[ab + 4];
                if (cc & 1) {
                    DO_CHUNK(qa, qb, whiA[cc], wloA[cc], aA1);
                    DO_CHUNK(qa, qb, whiB[cc], wloB[cc], aB1);
                } else {
                    DO_CHUNK(qa, qb, whiA[cc], wloA[cc], aA0);
                    DO_CHUNK(qa, qb, whiB[cc], wloB[cc], aB0);
                }
            }
        }
        // D row 0 (batch = chain) lives in lanes 0-15, reg .x
        if (ln < 16) {
            part[t & 1][w][ln]      = aA0.x + aA1.x;
            part[t & 1][w][16 + ln] = aB0.x + aB1.x;
        }
        __syncthreads();   // single barrier: partials ready

        if (w == 0 && ln < 32) {   // waves 1-3 proceed straight to the next poll
            float sum = part[t & 1][0][ln] + part[t & 1][1][ln]
                      + part[t & 1][2][ln] + part[t & 1][3][ln];
            int colp = col0 + ln;
            float x = xp + sum + bhh;
            float h = tanhf(x);
            uint32_t hi = f2bf(h);
            float hif = __builtin_bit_cast(float, hi << 16);
            uint32_t lo = f2bf(h - hif);
            uint32_t pk = (hi << 16) | lo;
            (void)__hip_atomic_exchange(ring + (size_t)(t & (RING - 1)) * 1024 + colp,
                                        pk, __ATOMIC_RELAXED, __HIP_MEMORY_SCOPE_AGENT);
            (void)__hip_atomic_exchange(ring + (size_t)((t + RING - 3) & (RING - 1)) * 1024 + colp,
                                        SEN, __ATOMIC_RELAXED, __HIP_MEMORY_SCOPE_AGENT);
            hs[(size_t)(t * NB + chain) * HID + colp] = (unsigned short)hi;
        }
    }
}

// ---------------- fc: C[m][n] = hs[m][:] . W_fc[n][:] + b_fc[n], bf16 MFMA ----------------
// R16 verbatim.
__global__ void k_fc(const unsigned short* __restrict__ A,   // [2048][1024] bf16
                     const unsigned short* __restrict__ Bw,  // [32000][1024] bf16
                     const float* __restrict__ bias,
                     float* __restrict__ out) {              // [8][256][32000] f32
    __shared__ __align__(16) unsigned short As[128 * 32];
    __shared__ __align__(16) unsigned short Bs[128 * 32];
    const int tid = threadIdx.x;
    const int w = tid >> 6, ln = tid & 63;
    const int bm = blockIdx.x, bn = blockIdx.y;
    const int wm = (w >> 1) * 64, wn = (w & 1) * 64;
    const int srow = tid >> 2;
    const int scol = (tid & 3) * 8;
    const unsigned short* Ag = A  + (size_t)(bm * 128 + srow) * 1024 + scol;
    const unsigned short* Bg = Bw + (size_t)(bn * 128 + srow) * 1024 + scol;
    unsigned short* ldsA0 = As + w * 512;
    unsigned short* ldsA1 = As + 2048 + w * 512;
    unsigned short* ldsB0 = Bs + w * 512;
    unsigned short* ldsB1 = Bs + 2048 + w * 512;

    f32x4 acc[4][4] = {};
    const int fr = ln & 15;
    const int kq = (ln >> 4) * 8;

    for (int kk = 0; kk < 1024; kk += 32) {
        __syncthreads();
        __builtin_amdgcn_global_load_lds((const AS1 void*)(Ag + kk),             (AS3 void*)ldsA0, 16, 0, 0);
        __builtin_amdgcn_global_load_lds((const AS1 void*)(Ag + 64 * 1024 + kk), (AS3 void*)ldsA1, 16, 0, 0);
        __builtin_amdgcn_global_load_lds((const AS1 void*)(Bg + kk),             (AS3 void*)ldsB0, 16, 0, 0);
        __builtin_amdgcn_global_load_lds((const AS1 void*)(Bg + 64 * 1024 + kk), (AS3 void*)ldsB1, 16, 0, 0);
        __syncthreads();
        bf16x8 af[4], bf[4];
#pragma unroll
        for (int i = 0; i < 4; ++i)
            af[i] = *(const bf16x8*)&As[(wm + i * 16 + fr) * 32 + kq];
#pragma unroll
        for (int j = 0; j < 4; ++j)
            bf[j] = *(const bf16x8*)&Bs[(wn + j * 16 + fr) * 32 + kq];
#pragma unroll
        for (int i = 0; i < 4; ++i)
#pragma unroll
            for (int j = 0; j < 4; ++j)
                acc[i][j] = __builtin_amdgcn_mfma_f32_16x16x32_bf16(af[i], bf[j], acc[i][j], 0, 0, 0);
    }

    const int fq = ln >> 4;
#pragma unroll
    for (int i = 0; i < 4; ++i) {
#pragma unroll
        for (int j = 0; j < 4; ++j) {
            int n = bn * 128 + wn + j * 16 + fr;
            float bv = bias[n];
#pragma unroll
            for (int r = 0; r < 4; ++r) {
                int m = bm * 128 + wm + i * 16 + fq * 4 + r;
                int t = m >> 3, b = m & 7;
                out[(size_t)b * T_SEQ * NOUT + (size_t)t * NOUT + n] = acc[i][j][r] + bv;
            }
        }
    }
}

extern "C" void kernel_launch(void* const* d_in, const int* in_sizes, int n_in,
                              void* d_out, int out_size, void* d_ws, size_t ws_size,
                              hipStream_t stream) {
    const int*   inputs = (const int*)d_in[0];
    const float* embed  = (const float*)d_in[1];
    const float* W_ih   = (const float*)d_in[2];
    const float* W_hh   = (const float*)d_in[3];
    const float* b_ih   = (const float*)d_in[4];
    const float* b_hh   = (const float*)d_in[5];
    const float* W_fc   = (const float*)d_in[6];
    const float* b_fc   = (const float*)d_in[7];
    float* out = (float*)d_out;

    char* ws = (char*)d_ws;
    unsigned int*   hpk   = (unsigned int*)(ws);                        // 512 KB
    float*          xproj = (float*)(ws + 524288);                      // 8 MB
    unsigned short* hs    = (unsigned short*)(ws + 524288 + 8388608);   // 4 MB
    unsigned short* wfcb  = (unsigned short*)(ws + 524288 + 8388608 + 4194304); // 64 MB

    k_prologue<<<2048, 256, 0, stream>>>(inputs, embed, W_ih, b_ih, xproj,
                                         hpk, W_fc, wfcb);
    k_rnn<<<256, 256, 0, stream>>>(W_hh, b_hh, xproj, hpk, hs);
    k_fc<<<dim3(16, 250), 256, 0, stream>>>(hs, wfcb, b_fc, out);
}

// Round 18
// 671.549 us; speedup vs baseline: 1.6823x; 1.0037x over previous
//
#include <hip/hip_runtime.h>
#include <stdint.h>

#define T_SEQ 256
#define NB    8
#define EMB   512
#define HID   1024
#define NOUT  32000
#define RING  16
#define SEN   0x40004000u

typedef float    f32x4  __attribute__((ext_vector_type(4)));
typedef unsigned int u32x4 __attribute__((ext_vector_type(4)));
typedef __bf16   bf16x8 __attribute__((ext_vector_type(8)));

#define AS1 __attribute__((address_space(1)))
#define AS3 __attribute__((address_space(3)))

__device__ __forceinline__ uint32_t f2bf(float f) {
    uint32_t u = __builtin_bit_cast(uint32_t, f);
    u += 0x7FFFu + ((u >> 16) & 1u);   // RNE
    return (u >> 16);
}

__device__ __forceinline__ bf16x8 mk_hi(u32x4 a, u32x4 b) {
    u32x4 r;
    r.x = __builtin_amdgcn_perm(a.y, a.x, 0x07060302u);
    r.y = __builtin_amdgcn_perm(a.w, a.z, 0x07060302u);
    r.z = __builtin_amdgcn_perm(b.y, b.x, 0x07060302u);
    r.w = __builtin_amdgcn_perm(b.w, b.z, 0x07060302u);
    return __builtin_bit_cast(bf16x8, r);
}
__device__ __forceinline__ bf16x8 mk_lo(u32x4 a, u32x4 b) {
    u32x4 r;
    r.x = __builtin_amdgcn_perm(a.y, a.x, 0x05040100u);
    r.y = __builtin_amdgcn_perm(a.w, a.z, 0x05040100u);
    r.z = __builtin_amdgcn_perm(b.y, b.x, 0x05040100u);
    r.w = __builtin_amdgcn_perm(b.w, b.z, 0x05040100u);
    return __builtin_bit_cast(bf16x8, r);
}

// ======== prologue: blocks 0-127 fill ring; 128-639 xproj; 640-2047 convert ========
// R16 verbatim (proven).
__global__ __launch_bounds__(256) void k_prologue(
        const int* __restrict__ inputs, const float* __restrict__ embed,
        const float* __restrict__ W_ih, const float* __restrict__ b_ih,
        float* __restrict__ xproj,
        unsigned int* __restrict__ hpk,                 // 8*RING*1024 u32 = 512 KB
        const float* __restrict__ W_fc, unsigned short* __restrict__ wfcb) {
    const int blk = blockIdx.x;
    const int tid = threadIdx.x;

    if (blk < 128) {
        int i = blk * 256 + tid;
        unsigned int* a = hpk + (size_t)i * 4;
#pragma unroll
        for (int j = 0; j < 4; ++j)
            (void)__hip_atomic_exchange(a + j, SEN, __ATOMIC_RELAXED, __HIP_MEMORY_SCOPE_AGENT);
        return;
    }

    if (blk < 640) {
        __shared__ float As[64][33];
        __shared__ float Bs[64][33];
        __shared__ int   idx_s[64];
        const int idx = blk - 128;
        const int bm = idx >> 4, bn = idx & 15;
        if (tid < 64) {
            int m = bm * 64 + tid;
            idx_s[tid] = inputs[(m & 7) * T_SEQ + (m >> 3)];
        }
        __syncthreads();
        const int ty = tid >> 4, tx = tid & 15;
        const int lr = tid >> 2, lc = (tid & 3) * 8;
        float acc[4][4] = {};
        for (int kk = 0; kk < EMB; kk += 32) {
            __syncthreads();
            const float* arow = embed + (size_t)idx_s[lr] * EMB + kk + lc;
            f32x4 a0 = *(const f32x4*)arow;
            f32x4 a1 = *(const f32x4*)(arow + 4);
            const float* brow = W_ih + (size_t)(bn * 64 + lr) * EMB + kk + lc;
            f32x4 b0 = *(const f32x4*)brow;
            f32x4 b1 = *(const f32x4*)(brow + 4);
#pragma unroll
            for (int u = 0; u < 4; ++u) {
                As[lr][lc + u] = a0[u]; As[lr][lc + 4 + u] = a1[u];
                Bs[lr][lc + u] = b0[u]; Bs[lr][lc + 4 + u] = b1[u];
            }
            __syncthreads();
#pragma unroll
            for (int k = 0; k < 32; ++k) {
                float av[4], bv[4];
#pragma unroll
                for (int i = 0; i < 4; ++i) av[i] = As[ty * 4 + i][k];
#pragma unroll
                for (int j = 0; j < 4; ++j) bv[j] = Bs[tx * 4 + j][k];
#pragma unroll
                for (int i = 0; i < 4; ++i)
#pragma unroll
                    for (int j = 0; j < 4; ++j) acc[i][j] += av[i] * bv[j];
            }
        }
#pragma unroll
        for (int i = 0; i < 4; ++i) {
            int m = bm * 64 + ty * 4 + i;
#pragma unroll
            for (int j = 0; j < 4; ++j) {
                int n = bn * 64 + tx * 4 + j;
                xproj[(size_t)m * HID + n] = acc[i][j] + b_ih[n];
            }
        }
        return;
    }

    {
        int i = (blk - 640) * 256 + tid;
        const f32x4* s4 = (const f32x4*)W_fc;
        int n4 = NOUT * HID / 4;
        int stride = 1408 * 256;
        for (int idx2 = i; idx2 < n4; idx2 += stride) {
            f32x4 v = s4[idx2];
            uint2 o;
            o.x = f2bf(v.x) | (f2bf(v.y) << 16);
            o.y = f2bf(v.z) | (f2bf(v.w) << 16);
            ((uint2*)wfcb)[idx2] = o;
        }
    }
}

// ========== recurrence: 8 chains x 32 blocks; waves = K-QUARTERS (R17 base) ==========
// R18 change: epilogue role-split. wave0 = join+tanh+pk PUBLISH ONLY (the
// consumer-gating store issues earlier); wave1 = sentinel refills (no data dep;
// slot t+13 safety proof is wave-independent); wave2 = recompute identical h
// (same LDS partials, same ops -> bit-identical) + hs archive; wave3 = straight
// to next poll. Coherence primitives bit-identical to R11/R16/R17
// (single-load vmcnt(0) poll; counted-vmcnt BLACKLISTED).
#define DO_CHUNK(qa, qb, WH, WL, ACC) do {                                      \
    bf16x8 ah = mk_hi(qa, qb);                                                  \
    bf16x8 al = mk_lo(qa, qb);                                                  \
    ACC = __builtin_amdgcn_mfma_f32_16x16x32_bf16(ah, WH, ACC, 0, 0, 0);        \
    ACC = __builtin_amdgcn_mfma_f32_16x16x32_bf16(al, WH, ACC, 0, 0, 0);        \
    ACC = __builtin_amdgcn_mfma_f32_16x16x32_bf16(ah, WL, ACC, 0, 0, 0);        \
} while (0)

__global__ __launch_bounds__(256, 1) void k_rnn(
        const float* __restrict__ W_hh, const float* __restrict__ b_hh,
        const float* __restrict__ xproj,
        unsigned int* __restrict__ hpk /* [8][RING][1024] u32 */,
        unsigned short* __restrict__ hs /* [2048][1024] bf16 */) {
    __shared__ __align__(16) unsigned int hlds[1024];   // 4 KB, wave-private quarters
    __shared__ float part[2][4][32];                     // 1 KB join, dbuf by t&1
    const int tid = threadIdx.x;
    const int w   = tid >> 6;
    const int ln  = tid & 63;
    const int blk = blockIdx.x;
    const int chain  = blk >> 5;
    const int member = blk & 31;
    const int col0 = member * 32;
    unsigned int* ring = hpk + (size_t)chain * (RING * 1024);

    // W fragments: col-group A (col0..+15) and B (col0+16..+31), K-quarter w.
    const float* wrowA = W_hh + (size_t)(col0 + (ln & 15)) * HID;
    const float* wrowB = W_hh + (size_t)(col0 + 16 + (ln & 15)) * HID;
    bf16x8 whiA[8], wloA[8], whiB[8], wloB[8];
#pragma unroll
    for (int cc = 0; cc < 8; ++cc) {
        int k0 = w * 256 + cc * 32 + (ln >> 4) * 8;
#pragma unroll
        for (int g = 0; g < 2; ++g) {
            const float* wr = g ? wrowB : wrowA;
            f32x4 wa = *(const f32x4*)(wr + k0);
            f32x4 wb = *(const f32x4*)(wr + k0 + 4);
            float wv[8] = { wa.x, wa.y, wa.z, wa.w, wb.x, wb.y, wb.z, wb.w };
            uint32_t hu[8], lu[8];
#pragma unroll
            for (int j = 0; j < 8; ++j) {
                hu[j] = f2bf(wv[j]);
                float hif = __builtin_bit_cast(float, hu[j] << 16);
                lu[j] = f2bf(wv[j] - hif);
            }
            u32x4 ph = { hu[0] | (hu[1] << 16), hu[2] | (hu[3] << 16),
                         hu[4] | (hu[5] << 16), hu[6] | (hu[7] << 16) };
            u32x4 pl = { lu[0] | (lu[1] << 16), lu[2] | (lu[3] << 16),
                         lu[4] | (lu[5] << 16), lu[6] | (lu[7] << 16) };
            if (g) { whiB[cc] = __builtin_bit_cast(bf16x8, ph); wloB[cc] = __builtin_bit_cast(bf16x8, pl); }
            else   { whiA[cc] = __builtin_bit_cast(bf16x8, ph); wloA[cc] = __builtin_bit_cast(bf16x8, pl); }
        }
    }
    // bhh for epilogue waves (0 = publisher, 2 = hs archiver)
    const float bhh = ((w == 0 || w == 2) && ln < 32) ? b_hh[col0 + ln] : 0.f;

    for (int t = 0; t < T_SEQ; ++t) {
        // xproj prefetch for epilogue waves, hidden under the poll
        float xp = 0.f;
        if ((w == 0 || w == 2) && ln < 32)
            xp = xproj[(size_t)(t * NB + chain) * HID + col0 + ln];

        if (t > 0) {
            // poll own K-quarter: ONE dwordx4 per lane, vmcnt(0) (R11-proven form)
            const unsigned int* hp = ring + (size_t)((t - 1) & (RING - 1)) * 1024
                                          + w * 256 + ln * 4;
            u32x4 q;
            do {
                asm volatile("global_load_dwordx4 %0, %1, off sc0 sc1\n\t"
                             "s_waitcnt vmcnt(0)"
                             : "=&v"(q) : "v"(hp) : "memory");
            } while (q.x == SEN || q.y == SEN || q.z == SEN || q.w == SEN);
            // wave-private stage; in-wave RAW fence (rule #18 pattern)
            *(u32x4*)&hlds[w * 256 + ln * 4] = q;
            asm volatile("s_waitcnt lgkmcnt(0)" ::: "memory");
            __builtin_amdgcn_sched_barrier(0);
        }

        f32x4 aA0 = {0.f,0.f,0.f,0.f}, aA1 = {0.f,0.f,0.f,0.f};
        f32x4 aB0 = {0.f,0.f,0.f,0.f}, aB1 = {0.f,0.f,0.f,0.f};
        if (t > 0) {
            const int lsub = (ln >> 4) * 8;
#pragma unroll
            for (int cc = 0; cc < 8; ++cc) {
                int ab = w * 256 + cc * 32 + lsub;
                u32x4 qa = *(const u32x4*)&hlds[ab];
                u32x4 qb = *(const u32x4*)&hlds[ab + 4];
                if (cc & 1) {
                    DO_CHUNK(qa, qb, whiA[cc], wloA[cc], aA1);
                    DO_CHUNK(qa, qb, whiB[cc], wloB[cc], aB1);
                } else {
                    DO_CHUNK(qa, qb, whiA[cc], wloA[cc], aA0);
                    DO_CHUNK(qa, qb, whiB[cc], wloB[cc], aB0);
                }
            }
        }
        if (ln < 16) {
            part[t & 1][w][ln]      = aA0.x + aA1.x;
            part[t & 1][w][16 + ln] = aB0.x + aB1.x;
        }
        __syncthreads();   // single barrier: partials ready

        if (w == 0 && ln < 32) {
            // PUBLISH role: join + tanh + pk atomic (consumer-gating) ONLY
            float sum = part[t & 1][0][ln] + part[t & 1][1][ln]
                      + part[t & 1][2][ln] + part[t & 1][3][ln];
            int colp = col0 + ln;
            float x = xp + sum + bhh;
            float h = tanhf(x);
            uint32_t hi = f2bf(h);
            float hif = __builtin_bit_cast(float, hi << 16);
            uint32_t lo = f2bf(h - hif);
            uint32_t pk = (hi << 16) | lo;
            (void)__hip_atomic_exchange(ring + (size_t)(t & (RING - 1)) * 1024 + colp,
                                        pk, __ATOMIC_RELAXED, __HIP_MEMORY_SCOPE_AGENT);
        } else if (w == 1 && ln < 32) {
            // REFILL role: sentinel for slot t+13 (no data dependency)
            int colp = col0 + ln;
            (void)__hip_atomic_exchange(ring + (size_t)((t + RING - 3) & (RING - 1)) * 1024 + colp,
                                        SEN, __ATOMIC_RELAXED, __HIP_MEMORY_SCOPE_AGENT);
        } else if (w == 2 && ln < 32) {
            // ARCHIVE role: recompute identical h (same inputs/ops), store hs
            float sum = part[t & 1][0][ln] + part[t & 1][1][ln]
                      + part[t & 1][2][ln] + part[t & 1][3][ln];
            int colp = col0 + ln;
            float x = xp + sum + bhh;
            float h = tanhf(x);
            uint32_t hi = f2bf(h);
            hs[(size_t)(t * NB + chain) * HID + colp] = (unsigned short)hi;
        }
        // wave3: straight to next poll (fastest sampler)
    }
}

// ---------------- fc: C[m][n] = hs[m][:] . W_fc[n][:] + b_fc[n], bf16 MFMA ----------------
// R16 verbatim.
__global__ void k_fc(const unsigned short* __restrict__ A,   // [2048][1024] bf16
                     const unsigned short* __restrict__ Bw,  // [32000][1024] bf16
                     const float* __restrict__ bias,
                     float* __restrict__ out) {              // [8][256][32000] f32
    __shared__ __align__(16) unsigned short As[128 * 32];
    __shared__ __align__(16) unsigned short Bs[128 * 32];
    const int tid = threadIdx.x;
    const int w = tid >> 6, ln = tid & 63;
    const int bm = blockIdx.x, bn = blockIdx.y;
    const int wm = (w >> 1) * 64, wn = (w & 1) * 64;
    const int srow = tid >> 2;
    const int scol = (tid & 3) * 8;
    const unsigned short* Ag = A  + (size_t)(bm * 128 + srow) * 1024 + scol;
    const unsigned short* Bg = Bw + (size_t)(bn * 128 + srow) * 1024 + scol;
    unsigned short* ldsA0 = As + w * 512;
    unsigned short* ldsA1 = As + 2048 + w * 512;
    unsigned short* ldsB0 = Bs + w * 512;
    unsigned short* ldsB1 = Bs + 2048 + w * 512;

    f32x4 acc[4][4] = {};
    const int fr = ln & 15;
    const int kq = (ln >> 4) * 8;

    for (int kk = 0; kk < 1024; kk += 32) {
        __syncthreads();
        __builtin_amdgcn_global_load_lds((const AS1 void*)(Ag + kk),             (AS3 void*)ldsA0, 16, 0, 0);
        __builtin_amdgcn_global_load_lds((const AS1 void*)(Ag + 64 * 1024 + kk), (AS3 void*)ldsA1, 16, 0, 0);
        __builtin_amdgcn_global_load_lds((const AS1 void*)(Bg + kk),             (AS3 void*)ldsB0, 16, 0, 0);
        __builtin_amdgcn_global_load_lds((const AS1 void*)(Bg + 64 * 1024 + kk), (AS3 void*)ldsB1, 16, 0, 0);
        __syncthreads();
        bf16x8 af[4], bf[4];
#pragma unroll
        for (int i = 0; i < 4; ++i)
            af[i] = *(const bf16x8*)&As[(wm + i * 16 + fr) * 32 + kq];
#pragma unroll
        for (int j = 0; j < 4; ++j)
            bf[j] = *(const bf16x8*)&Bs[(wn + j * 16 + fr) * 32 + kq];
#pragma unroll
        for (int i = 0; i < 4; ++i)
#pragma unroll
            for (int j = 0; j < 4; ++j)
                acc[i][j] = __builtin_amdgcn_mfma_f32_16x16x32_bf16(af[i], bf[j], acc[i][j], 0, 0, 0);
    }

    const int fq = ln >> 4;
#pragma unroll
    for (int i = 0; i < 4; ++i) {
#pragma unroll
        for (int j = 0; j < 4; ++j) {
            int n = bn * 128 + wn + j * 16 + fr;
            float bv = bias[n];
#pragma unroll
            for (int r = 0; r < 4; ++r) {
                int m = bm * 128 + wm + i * 16 + fq * 4 + r;
                int t = m >> 3, b = m & 7;
                out[(size_t)b * T_SEQ * NOUT + (size_t)t * NOUT + n] = acc[i][j][r] + bv;
            }
        }
    }
}

extern "C" void kernel_launch(void* const* d_in, const int* in_sizes, int n_in,
                              void* d_out, int out_size, void* d_ws, size_t ws_size,
                              hipStream_t stream) {
    const int*   inputs = (const int*)d_in[0];
    const float* embed  = (const float*)d_in[1];
    const float* W_ih   = (const float*)d_in[2];
    const float* W_hh   = (const float*)d_in[3];
    const float* b_ih   = (const float*)d_in[4];
    const float* b_hh   = (const float*)d_in[5];
    const float* W_fc   = (const float*)d_in[6];
    const float* b_fc   = (const float*)d_in[7];
    float* out = (float*)d_out;

    char* ws = (char*)d_ws;
    unsigned int*   hpk   = (unsigned int*)(ws);                        // 512 KB
    float*          xproj = (float*)(ws + 524288);                      // 8 MB
    unsigned short* hs    = (unsigned short*)(ws + 524288 + 8388608);   // 4 MB
    unsigned short* wfcb  = (unsigned short*)(ws + 524288 + 8388608 + 4194304); // 64 MB

    k_prologue<<<2048, 256, 0, stream>>>(inputs, embed, W_ih, b_ih, xproj,
                                         hpk, W_fc, wfcb);
    k_rnn<<<256, 256, 0, stream>>>(W_hh, b_hh, xproj, hpk, hs);
    k_fc<<<dim3(16, 250), 256, 0, stream>>>(hs, wfcb, b_fc, out);
}